// Round 1
// baseline (1035.712 us; speedup 1.0000x reference)
//
#include <hip/hip_runtime.h>
#include <stdint.h>

// Problem dims
#define MROWS 32768   // B*T
#define TSEQ  1024
#define BBATCH 32
#define INDIM 1536
#define DDIM  768
#define NCAT  2304    // un_emb (768) + pw_x (768) + pw_y (768)

typedef short short8 __attribute__((ext_vector_type(8)));
typedef float f32x4  __attribute__((ext_vector_type(4)));

__device__ __forceinline__ float b2f(ushort u) {
    union { uint32_t u; float f; } x; x.u = ((uint32_t)u) << 16; return x.f;
}
__device__ __forceinline__ ushort f2b(float f) {
    union { float f; uint32_t u; } x; x.f = f;
    uint32_t r = x.u + 0x7fffu + ((x.u >> 16) & 1u);
    return (ushort)(r >> 16);
}

// ---------------- fp32 -> bf16 conversion (vectorized x4) ----------------
__global__ void cvt_bf16(const float* __restrict__ in, ushort* __restrict__ out, int n4) {
    int i = blockIdx.x * blockDim.x + threadIdx.x;
    if (i < n4) {
        float4 v = ((const float4*)in)[i];
        ushort4 o;
        o.x = f2b(v.x); o.y = f2b(v.y); o.z = f2b(v.z); o.w = f2b(v.w);
        ((ushort4*)out)[i] = o;
    }
}

// ---------------- bf16 GEMM: C[M,N] = A[M,K] * B[N,K]^T + bias, optional relu on cols < relu_ncols
// 128x128 tile / block, 4 waves (2x2), each wave 64x64 = 4x4 MFMA 16x16x32 subtiles.
// global_load_lds width=16 staging (m97 structure). Requires M%128==0, N%128==0, K%32==0.
__global__ __launch_bounds__(256, 2)
void gemm_bt(const ushort* __restrict__ A, const ushort* __restrict__ Bm,
             const float* __restrict__ bias, ushort* __restrict__ C,
             int M, int N, int K, int relu_ncols)
{
    __shared__ __align__(16) ushort lA[128 * 32];  // 8 KB
    __shared__ __align__(16) ushort lB[128 * 32];  // 8 KB

    const int tid  = threadIdx.x;
    const int lane = tid & 63, wave = tid >> 6;
    const int wm = wave & 1, wn = wave >> 1;       // 2x2 wave grid
    const int quad = lane >> 4, r16 = lane & 15;
    const int m0 = blockIdx.x * 128, n0 = blockIdx.y * 128;
    // staging decomposition: tile 128x32 = 8 segments of 16 rows; lane covers 8 elems
    const int srow = lane >> 2;          // 0..15 within segment
    const int scol = (lane & 3) * 8;     // 0,8,16,24

    f32x4 acc[4][4] = {};

    const int kIters = K >> 5;
    for (int kt = 0; kt < kIters; ++kt) {
        const int k0 = kt << 5;
        __syncthreads();   // previous iteration's LDS reads complete
#pragma unroll
        for (int c = 0; c < 2; ++c) {
            int seg = wave * 2 + c;
            int row = seg * 16 + srow;
            const ushort* ga = A + (size_t)(m0 + row) * K + k0 + scol;
            __builtin_amdgcn_global_load_lds(
                (const __attribute__((address_space(1))) void*)ga,
                (__attribute__((address_space(3))) void*)&lA[seg * 512], 16, 0, 0);
            const ushort* gb = Bm + (size_t)(n0 + row) * K + k0 + scol;
            __builtin_amdgcn_global_load_lds(
                (const __attribute__((address_space(1))) void*)gb,
                (__attribute__((address_space(3))) void*)&lB[seg * 512], 16, 0, 0);
        }
        __syncthreads();   // staging complete (compiler emits vmcnt(0) before barrier)

        short8 af[4], bf[4];
#pragma unroll
        for (int i = 0; i < 4; ++i)
            af[i] = *(const short8*)&lA[(wm * 64 + i * 16 + r16) * 32 + quad * 8];
#pragma unroll
        for (int j = 0; j < 4; ++j)
            bf[j] = *(const short8*)&lB[(wn * 64 + j * 16 + r16) * 32 + quad * 8];
#pragma unroll
        for (int i = 0; i < 4; ++i)
#pragma unroll
            for (int j = 0; j < 4; ++j)
                acc[i][j] = __builtin_amdgcn_mfma_f32_16x16x32_bf16(af[i], bf[j], acc[i][j], 0, 0, 0);
    }

    // epilogue: C/D layout col = lane&15, row = quad*4 + reg  [m89-verified]
#pragma unroll
    for (int j = 0; j < 4; ++j) {
        int gn = n0 + wn * 64 + j * 16 + r16;
        float bv = bias[gn];
        bool dorelu = gn < relu_ncols;
#pragma unroll
        for (int i = 0; i < 4; ++i) {
            int gmb = m0 + wm * 64 + i * 16 + quad * 4;
#pragma unroll
            for (int rr = 0; rr < 4; ++rr) {
                float v = acc[i][j][rr] + bv;
                if (dorelu) v = fmaxf(v, 0.f);
                C[(size_t)(gmb + rr) * N + gn] = f2b(v);
            }
        }
    }
}

// ---------------- per-row stats over G3=[M,2304] (e | xe | ye), bf16 ----------------
// un_pot[m] = sum(e*urw)+urb ; rnx[m]=1/||xe|| ; rny[m]=1/||ye||
__global__ void row_stats_k(const ushort* __restrict__ G3, const float* __restrict__ urw,
                            const float* __restrict__ urb, float* __restrict__ un_pot,
                            float* __restrict__ rnx, float* __restrict__ rny)
{
    int m = blockIdx.x, tid = threadIdx.x;
    const ushort* row = G3 + (size_t)m * NCAT;
    float se = 0.f, sx = 0.f, sy = 0.f;
    for (int t = tid; t < DDIM; t += 256) {
        float ev = b2f(row[t]);          se += ev * urw[t];
        float xv = b2f(row[DDIM + t]);   sx += xv * xv;
        float yv = b2f(row[2*DDIM + t]); sy += yv * yv;
    }
    for (int off = 32; off; off >>= 1) {
        se += __shfl_down(se, off, 64);
        sx += __shfl_down(sx, off, 64);
        sy += __shfl_down(sy, off, 64);
    }
    __shared__ float rb[3][4];
    int lane = tid & 63, w = tid >> 6;
    if (lane == 0) { rb[0][w] = se; rb[1][w] = sx; rb[2][w] = sy; }
    __syncthreads();
    if (tid == 0) {
        float a = rb[0][0] + rb[0][1] + rb[0][2] + rb[0][3];
        float nx = sqrtf(rb[1][0] + rb[1][1] + rb[1][2] + rb[1][3]);
        float ny = sqrtf(rb[2][0] + rb[2][1] + rb[2][2] + rb[2][3]);
        un_pot[m] = a + urb[0];
        rnx[m] = 1.f / fmaxf(nx, 1e-12f);
        rny[m] = 1.f / fmaxf(ny, 1e-12f);
    }
}

// ---------------- ybar[b,d] = (1/T) * sum_s ye[b,s,d] * rny[b,s] ----------------
__global__ void ybar_k(const ushort* __restrict__ G3, const float* __restrict__ rny,
                       float* __restrict__ ybar)
{
    int blk = blockIdx.x, b = blk / 3;
    int d = (blk % 3) * 256 + threadIdx.x;
    __shared__ float sr[256];
    float acc = 0.f;
    for (int s0 = 0; s0 < TSEQ; s0 += 256) {
        __syncthreads();
        sr[threadIdx.x] = rny[b * TSEQ + s0 + threadIdx.x];
        __syncthreads();
        for (int s = 0; s < 256; ++s)
            acc += b2f(G3[(size_t)(b * TSEQ + s0 + s) * NCAT + 2*DDIM + d]) * sr[s];
    }
    ybar[b * DDIM + d] = acc * (1.0f / TSEQ);
}

// ---------------- scores[m] = rw0*un_pot + rw1 * rnx[m]*dot(xe[m], ybar[b]) ----------------
__global__ void pw_scores_k(const ushort* __restrict__ G3, const float* __restrict__ ybar,
                            const float* __restrict__ rnx, const float* __restrict__ un_pot,
                            const float* __restrict__ red_w, float* __restrict__ scores)
{
    int m = blockIdx.x, tid = threadIdx.x;
    int b = m >> 10;
    const ushort* xer = G3 + (size_t)m * NCAT + DDIM;
    const float* yb = ybar + b * DDIM;
    float s = 0.f;
    for (int t = tid; t < DDIM; t += 256) s += b2f(xer[t]) * yb[t];
    for (int off = 32; off; off >>= 1) s += __shfl_down(s, off, 64);
    __shared__ float rb[4];
    int lane = tid & 63, w = tid >> 6;
    if (lane == 0) rb[w] = s;
    __syncthreads();
    if (tid == 0) {
        float dot = rb[0] + rb[1] + rb[2] + rb[3];
        scores[m] = red_w[0] * un_pot[m] + red_w[1] * (rnx[m] * dot);
    }
}

// ---------------- softmax over T per batch ----------------
__global__ void softmax_k(const float* __restrict__ scores, float* __restrict__ wsm)
{
    int b = blockIdx.x, tid = threadIdx.x;
    float v[4];
    float lm = -1e30f;
#pragma unroll
    for (int i = 0; i < 4; ++i) {
        v[i] = scores[b * TSEQ + i * 256 + tid];
        lm = fmaxf(lm, v[i]);
    }
    for (int off = 32; off; off >>= 1) lm = fmaxf(lm, __shfl_down(lm, off, 64));
    __shared__ float rb[4];
    __shared__ float smax, ssum;
    int lane = tid & 63, w = tid >> 6;
    if (lane == 0) rb[w] = lm;
    __syncthreads();
    if (tid == 0) smax = fmaxf(fmaxf(rb[0], rb[1]), fmaxf(rb[2], rb[3]));
    __syncthreads();
    float e[4];
    float ls = 0.f;
#pragma unroll
    for (int i = 0; i < 4; ++i) { e[i] = expf(v[i] - smax); ls += e[i]; }
    for (int off = 32; off; off >>= 1) ls += __shfl_down(ls, off, 64);
    __syncthreads();
    if (lane == 0) rb[w] = ls;
    __syncthreads();
    if (tid == 0) ssum = rb[0] + rb[1] + rb[2] + rb[3];
    __syncthreads();
    float inv = 1.f / ssum;
#pragma unroll
    for (int i = 0; i < 4; ++i) wsm[b * TSEQ + i * 256 + tid] = e[i] * inv;
}

// ---------------- out[b,d] = sum_t wsm[b,t] * u[b,t,d] ----------------
__global__ void out_k(const ushort* __restrict__ U16, const float* __restrict__ wsm,
                      float* __restrict__ out)
{
    int blk = blockIdx.x, b = blk / 3;
    int d = (blk % 3) * 256 + threadIdx.x;
    __shared__ float sw[256];
    float acc = 0.f;
    for (int t0 = 0; t0 < TSEQ; t0 += 256) {
        __syncthreads();
        sw[threadIdx.x] = wsm[b * TSEQ + t0 + threadIdx.x];
        __syncthreads();
        for (int t = 0; t < 256; ++t)
            acc += b2f(U16[(size_t)(b * TSEQ + t0 + t) * DDIM + d]) * sw[t];
    }
    out[b * DDIM + d] = acc;
}

// ---------------- workspace layout (bytes) ----------------
// G3 (e|xe|ye bf16, 151 MB) aliases the X16+H16 region (dead after GEMM2).
static const size_t O_X16   = 0;            // 32768*1536*2 = 100663296
static const size_t O_H16   = 100663296;    // 100663296
static const size_t O_G3    = 0;            // 150994944 (alias)
static const size_t O_U16   = 201326592;    // 50331648
static const size_t O_W1    = 251658240;    // 4718592
static const size_t O_W2    = 256376832;    // 2359296
static const size_t O_W3    = 258736128;    // 3538944
static const size_t O_B3    = 262275072;    // 9216
static const size_t O_UNPOT = 262284288;    // 131072
static const size_t O_RNX   = 262415360;    // 131072
static const size_t O_RNY   = 262546432;    // 131072
static const size_t O_SCORE = 262677504;    // 131072
static const size_t O_WSM   = 262808576;    // 131072
static const size_t O_YBAR  = 262939648;    // 98304
// total: 263037952 bytes (~263 MB)

extern "C" void kernel_launch(void* const* d_in, const int* in_sizes, int n_in,
                              void* d_out, int out_size, void* d_ws, size_t ws_size,
                              hipStream_t stream)
{
    const float* x        = (const float*)d_in[0];
    const float* fc1_w    = (const float*)d_in[1];
    const float* fc1_b    = (const float*)d_in[2];
    const float* fc2_w    = (const float*)d_in[3];
    const float* fc2_b    = (const float*)d_in[4];
    const float* un_emb_w = (const float*)d_in[5];
    const float* un_emb_b = (const float*)d_in[6];
    const float* un_red_w = (const float*)d_in[7];
    const float* un_red_b = (const float*)d_in[8];
    const float* pw_x_w   = (const float*)d_in[9];
    const float* pw_x_b   = (const float*)d_in[10];
    const float* pw_y_w   = (const float*)d_in[11];
    const float* pw_y_b   = (const float*)d_in[12];
    const float* red_w    = (const float*)d_in[13];

    char* ws = (char*)d_ws;
    ushort* X16 = (ushort*)(ws + O_X16);
    ushort* H16 = (ushort*)(ws + O_H16);
    ushort* G3  = (ushort*)(ws + O_G3);
    ushort* U16 = (ushort*)(ws + O_U16);
    ushort* W1  = (ushort*)(ws + O_W1);
    ushort* W2  = (ushort*)(ws + O_W2);
    ushort* W3  = (ushort*)(ws + O_W3);
    float*  B3  = (float*)(ws + O_B3);
    float*  UNPOT = (float*)(ws + O_UNPOT);
    float*  RNX = (float*)(ws + O_RNX);
    float*  RNY = (float*)(ws + O_RNY);
    float*  SCORES = (float*)(ws + O_SCORE);
    float*  WSM = (float*)(ws + O_WSM);
    float*  YBAR = (float*)(ws + O_YBAR);

    // --- convert inputs to bf16 ---
    cvt_bf16<<<49152, 256, 0, stream>>>(x, X16, 12582912);               // 32768*1536/4
    cvt_bf16<<<2304, 256, 0, stream>>>(fc1_w, W1, 589824);               // 1536*1536/4
    cvt_bf16<<<1152, 256, 0, stream>>>(fc2_w, W2, 294912);               // 768*1536/4
    cvt_bf16<<<576, 256, 0, stream>>>(un_emb_w, W3, 147456);             // 768*768/4
    cvt_bf16<<<576, 256, 0, stream>>>(pw_x_w, W3 + 589824, 147456);
    cvt_bf16<<<576, 256, 0, stream>>>(pw_y_w, W3 + 1179648, 147456);

    // --- concat biases for the fused N=2304 GEMM ---
    hipMemcpyAsync(B3,        un_emb_b, 768 * 4, hipMemcpyDeviceToDevice, stream);
    hipMemcpyAsync(B3 + 768,  pw_x_b,   768 * 4, hipMemcpyDeviceToDevice, stream);
    hipMemcpyAsync(B3 + 1536, pw_y_b,   768 * 4, hipMemcpyDeviceToDevice, stream);

    // --- GEMM chain ---
    // h = relu(x @ fc1_w^T + fc1_b)            [M,1536]
    gemm_bt<<<dim3(MROWS / 128, INDIM / 128), 256, 0, stream>>>(
        X16, W1, fc1_b, H16, MROWS, INDIM, INDIM, INDIM);
    // u = h @ fc2_w^T + fc2_b                  [M,768]
    gemm_bt<<<dim3(MROWS / 128, DDIM / 128), 256, 0, stream>>>(
        H16, W2, fc2_b, U16, MROWS, DDIM, INDIM, 0);
    // [e|xe|ye] = u @ [un_emb|pw_x|pw_y]^T + b  [M,2304], relu on first 768 cols (e)
    gemm_bt<<<dim3(MROWS / 128, NCAT / 128), 256, 0, stream>>>(
        U16, W3, B3, G3, MROWS, NCAT, DDIM, DDIM);

    // --- reductions / attention ---
    row_stats_k<<<MROWS, 256, 0, stream>>>(G3, un_red_w, un_red_b, UNPOT, RNX, RNY);
    ybar_k<<<BBATCH * 3, 256, 0, stream>>>(G3, RNY, YBAR);
    pw_scores_k<<<MROWS, 256, 0, stream>>>(G3, YBAR, RNX, UNPOT, red_w, SCORES);
    softmax_k<<<BBATCH, 256, 0, stream>>>(SCORES, WSM);
    out_k<<<BBATCH * 3, 256, 0, stream>>>(U16, WSM, (float*)d_out);
}